// Round 12
// baseline (244.419 us; speedup 1.0000x reference)
//
#include <hip/hip_runtime.h>
#include <math.h>

// Problem constants: B=2, L=2048, E=1024, H=16, D=64
constexpr int Lc = 2048, Ec = 1024, Hc = 16, Dc = 64;

typedef __attribute__((ext_vector_type(8))) short bf16x8;
typedef __attribute__((ext_vector_type(4))) float f32x4;
typedef unsigned short u16;
typedef unsigned int u32;

#define MFMA16(a, b, c) __builtin_amdgcn_mfma_f32_16x16x32_bf16(a, b, c, 0, 0, 0)

__device__ inline u16 f2bf(float f) {
  u32 u = __builtin_bit_cast(u32, f);
  u32 r = u + 0x7fff + ((u >> 16) & 1);   // RNE
  return (u16)(r >> 16);
}

__device__ inline void gld16(const void* g, void* l) {
  __builtin_amdgcn_global_load_lds(
      (const __attribute__((address_space(1))) u32*)g,
      (__attribute__((address_space(3))) u32*)l, 16, 0, 0);
}

// =====================================================================
// Prepass: fp32 -> bf16 for x (4M), w_qkv Q+V rows (2M fused), w_out (1M).
// =====================================================================
constexpr size_t XN = (size_t)4096 * 1024;
constexpr size_t WQN = (size_t)2048 * 1024;
constexpr size_t WON = (size_t)1024 * 1024;

__global__ __launch_bounds__(256) void convert_all(
    const float* __restrict__ x, const float* __restrict__ wqkv,
    const float* __restrict__ wout, u16* __restrict__ xb,
    u16* __restrict__ wqb, u16* __restrict__ wob)
{
  const size_t i = ((size_t)blockIdx.x * 256 + threadIdx.x) * 4;
  float4 v;
  u16* dst;
  if (i < XN) {
    v = *(const float4*)(x + i);
    dst = xb + i;
  } else if (i < XN + WQN) {
    const size_t off = i - XN;
    const size_t row = off >> 10, col = off & 1023;
    const size_t srow = row + ((row >> 10) << 10);   // skip K rows of w_qkv
    v = *(const float4*)(wqkv + srow * 1024 + col);
    dst = wqb + off;
  } else {
    const size_t off = i - XN - WQN;
    v = *(const float4*)(wout + off);
    dst = wob + off;
  }
  u16 o0 = f2bf(v.x), o1 = f2bf(v.y), o2 = f2bf(v.z), o3 = f2bf(v.w);
  dst[0] = o0; dst[1] = o1; dst[2] = o2; dst[3] = o3;
}

// =====================================================================
// QV GEMM v7 (bf16 MFMA): M=4096, N=2048 (fused Q|V), K=1024.
// Unchanged from round 10 (BK=64, XOR swizzle, XCD-patch dispatch,
// fused Vt transpose store in epilogue).
// =====================================================================
__global__ __launch_bounds__(256) void gemm_qv(
    const u16* __restrict__ A, const u16* __restrict__ W,
    const float* __restrict__ bqkv, u16* __restrict__ Q, u16* __restrict__ V,
    u16* __restrict__ Vt)
{
  __shared__ __align__(16) u16 As[2][8192];   // 128 rows x 64 u16
  __shared__ __align__(16) u16 Bs[2][8192];
  const int tid = threadIdx.x;
  const int w = tid >> 6, lane = tid & 63;
  const int quad = lane >> 4, l16 = lane & 15;
  const int wm = w >> 1, wn = w & 1;

  // XCD-patch swizzle: grid rows R=32, cols C=16; patches 8x8.
  const int flat = blockIdx.x;
  const int xcd = flat & 7, s64 = flat >> 3;        // s64 in [0,64)
  const int pr = xcd >> 1, pc = xcd & 1;            // 4x2 patch grid
  const int rowTile = (pr * 8 + (s64 >> 3)) * 128;
  const int colTile = (pc * 8 + (s64 & 7)) * 128;

  // staging: dest byte b = tid*16 (+4096*j); row = b>>7 = srow+32j,
  // source element = b ^ ((row&7)<<4)  (row&7 invariant under +32)
  const int srow = tid >> 3;
  const int e = (((tid & 7) * 16) ^ ((srow & 7) << 4)) >> 1;   // u16 in [0,64)
  const u16* Asrc = A + (size_t)(rowTile + srow) * 1024 + e;
  const u16* Bsrc = W + (size_t)(colTile + srow) * 1024 + e;

  f32x4 acc[4][4] = {};

#define STAGE_QV(sb, k0)                                              \
  {                                                                   \
    gld16(Asrc + (k0),             &As[sb][tid * 8]);                 \
    gld16(Asrc + (k0) + 32 * 1024, &As[sb][tid * 8 + 2048]);          \
    gld16(Asrc + (k0) + 64 * 1024, &As[sb][tid * 8 + 4096]);          \
    gld16(Asrc + (k0) + 96 * 1024, &As[sb][tid * 8 + 6144]);          \
    gld16(Bsrc + (k0),             &Bs[sb][tid * 8]);                 \
    gld16(Bsrc + (k0) + 32 * 1024, &Bs[sb][tid * 8 + 2048]);          \
    gld16(Bsrc + (k0) + 64 * 1024, &Bs[sb][tid * 8 + 4096]);          \
    gld16(Bsrc + (k0) + 96 * 1024, &Bs[sb][tid * 8 + 6144]);          \
  }

  STAGE_QV(0, 0);
  int cur = 0;
  for (int k0 = 0; k0 < 1024; k0 += 64) {
    __syncthreads();                       // drains stage(k0) into buf[cur]
    if (k0 + 64 < 1024) STAGE_QV(cur ^ 1, k0 + 64);
    bf16x8 af[4][2], bf[4][2];
#pragma unroll
    for (int s = 0; s < 4; ++s)
#pragma unroll
      for (int kk = 0; kk < 2; ++kk)
        af[s][kk] = *(const bf16x8*)&As[cur][(wm * 64 + s * 16 + l16) * 64 +
                     ((kk * 32 + quad * 8) ^ ((l16 & 7) << 3))];
#pragma unroll
    for (int n = 0; n < 4; ++n)
#pragma unroll
      for (int kk = 0; kk < 2; ++kk)
        bf[n][kk] = *(const bf16x8*)&Bs[cur][(wn * 64 + n * 16 + l16) * 64 +
                     ((kk * 32 + quad * 8) ^ ((l16 & 7) << 3))];
#pragma unroll
    for (int kk = 0; kk < 2; ++kk)
#pragma unroll
      for (int s = 0; s < 4; ++s)
#pragma unroll
        for (int n = 0; n < 4; ++n)
          acc[s][n] = MFMA16(af[s][kk], bf[n][kk], acc[s][n]);
    cur ^= 1;
  }
#undef STAGE_QV

#pragma unroll
  for (int n = 0; n < 4; ++n) {
    const int gn = colTile + wn * 64 + n * 16 + l16;   // fused col 0..2047
    const bool isV = gn >= 1024;
    const float bias = bqkv[gn + (isV ? 1024 : 0)];
    const float scl = isV ? 1.0f : 0.125f;             // fold 1/sqrt(d) into Q
    const int h = (gn & 1023) >> 6, d = gn & 63;
    u16* dst = isV ? V : Q;
#pragma unroll
    for (int s = 0; s < 4; ++s) {
      const int gm0 = rowTile + wm * 64 + s * 16 + quad * 4;
      const int b = gm0 >> 11;             // whole tile within one batch
      ushort4 tv;
#pragma unroll
      for (int r = 0; r < 4; ++r) {
        const int l = (gm0 + r) & 2047;
        const u16 val = f2bf((acc[s][n][r] + bias) * scl);
        dst[(((size_t)(b * Hc + h)) * Lc + l) * Dc + d] = val;
        ((u16*)&tv)[r] = val;
      }
      if (isV) {                           // fused transpose store
        const int l0 = gm0 & 2047;
        *(ushort4*)(Vt + (((size_t)(b * Hc + h)) * Dc + d) * Lc + l0) = tv;
      }
    }
  }
}

// =====================================================================
// Flash attention v5 (bug-faithful: scores = Q.V^T, Q pre-scaled 1/8).
// NO LDS STAGING: per bh, V and Vt panels are 256KB each -- with the
// XCD swizzle 4bh/XCD = 1MB << 4MB L2, so staging L2-resident data
// through LDS was pure overhead (guide common-mistake #7 / m169).
// bv fragments load 16B/lane straight from V; bvt straight from Vt
// (row-contiguous).  All 4 waves read identical addresses -> L1
// broadcast.  ZERO __syncthreads (Ps is per-wave).  Structure (lo/hi
// q-tile fusion, grid 512, fragment math) identical to v3 otherwise.
// =====================================================================
constexpr int PSTR = 72;    // Ps row stride (u16)

__device__ inline void attn_half(
    const bf16x8 qf[2], const bf16x8 bv[4][2], const bf16x8 bvt[4][2],
    u16* __restrict__ Ps, f32x4 O[4], float lsum[4],
    int kt, int wq, bool needmask, int quad, int l16)
{
  // ---- S = Q V^T ----
  f32x4 sf[4] = {};
#pragma unroll
  for (int nb = 0; nb < 4; ++nb) {
    sf[nb] = MFMA16(qf[0], bv[nb][0], sf[nb]);
    sf[nb] = MFMA16(qf[1], bv[nb][1], sf[nb]);
  }
  // ---- exp + causal mask + partial row sums + P store ----
#pragma unroll
  for (int nb = 0; nb < 4; ++nb)
#pragma unroll
    for (int r = 0; r < 4; ++r) {
      float p = __expf(sf[nb][r]);        // scores bounded; Q pre-scaled
      if (needmask) {
        const int key = kt + nb * 16 + l16;
        const int qr = wq + quad * 4 + r;
        if (key > qr) p = 0.f;
      }
      lsum[r] += p;
      Ps[(quad * 4 + r) * PSTR + nb * 16 + l16] = f2bf(p);
    }
  // ---- O += P V ----
  bf16x8 pf[2];
#pragma unroll
  for (int kk = 0; kk < 2; ++kk)
    pf[kk] = *(const bf16x8*)&Ps[l16 * PSTR + kk * 32 + quad * 8];
#pragma unroll
  for (int db = 0; db < 4; ++db) {
    O[db] = MFMA16(pf[0], bvt[db][0], O[db]);
    O[db] = MFMA16(pf[1], bvt[db][1], O[db]);
  }
}

__global__ __launch_bounds__(256) void attn_mfma(
    const u16* __restrict__ Q, const u16* __restrict__ V,
    const u16* __restrict__ Vt, u16* __restrict__ outA)
{
  // LDS: only per-wave Ps transpose buffers (lo then hi).  18KB.
  __shared__ __align__(16) u16 PsAll[2 * 4 * 16 * PSTR];
  const int tid = threadIdx.x;
  const int w = tid >> 6, lane = tid & 63;
  const int quad = lane >> 4, l16 = lane & 15;

  // XCD-locality swizzle (hw round-robins linear id across 8 XCDs)
  const int flat = blockIdx.x;
  const int xcd = flat & 7, slot = flat >> 3;
  const int bh = xcd * 4 + (slot >> 4);
  const int xblk = slot & 15;
  const int b = bh >> 4, h = bh & 15;

  const u16* Qb = Q + (size_t)bh * Lc * Dc;
  const u16* Vb = V + (size_t)bh * Lc * Dc;
  const u16* Vtb = Vt + (size_t)bh * Dc * Lc;
  u16* Psl = &PsAll[w * 16 * PSTR];
  u16* Psh = &PsAll[(4 + w) * 16 * PSTR];

  const int qlo = xblk, qhi = 31 - xblk;
  const int nt = qhi + 1;                 // key tiles: union of both halves
  const int wqlo = qlo * 64 + w * 16;
  const int wqhi = qhi * 64 + w * 16;

  // Q fragments for both halves (A-operand)
  bf16x8 qfl[2], qfh[2];
#pragma unroll
  for (int kk = 0; kk < 2; ++kk) {
    qfl[kk] = *(const bf16x8*)(Qb + (size_t)(qlo * 64 + w * 16 + l16) * 64 + kk * 32 + quad * 8);
    qfh[kk] = *(const bf16x8*)(Qb + (size_t)(qhi * 64 + w * 16 + l16) * 64 + kk * 32 + quad * 8);
  }

  f32x4 Ol[4] = {}, Oh[4] = {};
  float lsl[4] = {0.f, 0.f, 0.f, 0.f}, lsh[4] = {0.f, 0.f, 0.f, 0.f};

  for (int t = 0; t < nt; ++t) {
    const int kt = t * 64;

    // B-operand fragments straight from L1/L2 (no LDS round-trip).
    // bv: V[kt + nb*16 + l16][kk*32 + quad*8 ..+7]  (16B/lane)
    // bvt: Vt[nb*16 + l16][kt + kk*32 + quad*8 ..+7] (16B/lane, contiguous)
    bf16x8 bv[4][2], bvt[4][2];
#pragma unroll
    for (int nb = 0; nb < 4; ++nb)
#pragma unroll
      for (int kk = 0; kk < 2; ++kk) {
        bv[nb][kk] = *(const bf16x8*)(Vb + (size_t)(kt + nb * 16 + l16) * 64 + kk * 32 + quad * 8);
        bvt[nb][kk] = *(const bf16x8*)(Vtb + (size_t)(nb * 16 + l16) * Lc + kt + kk * 32 + quad * 8);
      }

    // hi half computes every tile; mask only on its diagonal tile
    attn_half(qfh, bv, bvt, Psh, Oh, lsh, kt, wqhi, t == qhi, quad, l16);
    if (t <= qlo)                         // wave-uniform gate
      attn_half(qfl, bv, bvt, Psl, Ol, lsl, kt, wqlo, t == qlo, quad, l16);
  }

  // epilogue: reduce row sums over the 16 lanes, normalize, store
#pragma unroll
  for (int half = 0; half < 2; ++half) {
    const int q0 = half ? qhi * 64 : qlo * 64;
    const f32x4* O = half ? Oh : Ol;
    const float* ls = half ? lsh : lsl;
#pragma unroll
    for (int r = 0; r < 4; ++r) {
      float l = ls[r];
      l += __shfl_xor(l, 1);
      l += __shfl_xor(l, 2);
      l += __shfl_xor(l, 4);
      l += __shfl_xor(l, 8);
      const float inv = 1.f / l;
      const int q = q0 + w * 16 + quad * 4 + r;
      const int orow = h * 128 + (q >> 4);
      const int cbase = (q & 15) << 6;
#pragma unroll
      for (int db = 0; db < 4; ++db)
        outA[((size_t)b * Lc + orow) * Ec + cbase + db * 16 + l16] =
            f2bf(O[db][r] * inv);
    }
  }
}

// =====================================================================
// Out GEMM v6: out[m][n] = sum_k Aw[m][k]*wob[n][k] + b_out[n], fp32 out.
// Unchanged from round 10 (64x128 tile, BK=64, swizzle, XCD-patch).
// =====================================================================
__global__ __launch_bounds__(256) void gemm_out(
    const u16* __restrict__ A, const u16* __restrict__ W,
    const float* __restrict__ bias, float* __restrict__ out)
{
  __shared__ __align__(16) u16 As[2][4096];   // 64 rows x 64 u16
  __shared__ __align__(16) u16 Bs[2][8192];   // 128 rows x 64 u16
  const int tid = threadIdx.x;
  const int w = tid >> 6, lane = tid & 63;
  const int quad = lane >> 4, l16 = lane & 15;
  const int wm = w >> 1, wn = w & 1;          // wm: 2x32 rows, wn: 2x64 cols

  // XCD-patch swizzle: grid rows R=64, cols C=8; xcd owns 8 rows x 8 cols.
  const int flat = blockIdx.x;
  const int xcd = flat & 7, s64 = flat >> 3;        // s64 in [0,64)
  const int rowTile = (xcd * 8 + (s64 >> 3)) * 64;
  const int colTile = (s64 & 7) * 128;

  const int srow = tid >> 3;
  const int e = (((tid & 7) * 16) ^ ((srow & 7) << 4)) >> 1;   // u16 in [0,64)
  const u16* Asrc = A + (size_t)(rowTile + srow) * 1024 + e;
  const u16* Bsrc = W + (size_t)(colTile + srow) * 1024 + e;

  f32x4 acc[2][4] = {};

#define STAGE_OUT(sb, k0)                                             \
  {                                                                   \
    gld16(Asrc + (k0),             &As[sb][tid * 8]);                 \
    gld16(Asrc + (k0) + 32 * 1024, &As[sb][tid * 8 + 2048]);          \
    gld16(Bsrc + (k0),             &Bs[sb][tid * 8]);                 \
    gld16(Bsrc + (k0) + 32 * 1024, &Bs[sb][tid * 8 + 2048]);          \
    gld16(Bsrc + (k0) + 64 * 1024, &Bs[sb][tid * 8 + 4096]);          \
    gld16(Bsrc + (k0) + 96 * 1024, &Bs[sb][tid * 8 + 6144]);          \
  }

  STAGE_OUT(0, 0);
  int cur = 0;
  for (int k0 = 0; k0 < 1024; k0 += 64) {
    __syncthreads();
    if (k0 + 64 < 1024) STAGE_OUT(cur ^ 1, k0 + 64);
    bf16x8 af[2][2], bf[4][2];
#pragma unroll
    for (int s = 0; s < 2; ++s)
#pragma unroll
      for (int kk = 0; kk < 2; ++kk)
        af[s][kk] = *(const bf16x8*)&As[cur][(wm * 32 + s * 16 + l16) * 64 +
                     ((kk * 32 + quad * 8) ^ ((l16 & 7) << 3))];
#pragma unroll
    for (int n = 0; n < 4; ++n)
#pragma unroll
      for (int kk = 0; kk < 2; ++kk)
        bf[n][kk] = *(const bf16x8*)&Bs[cur][(wn * 64 + n * 16 + l16) * 64 +
                     ((kk * 32 + quad * 8) ^ ((l16 & 7) << 3))];
#pragma unroll
    for (int kk = 0; kk < 2; ++kk)
#pragma unroll
      for (int s = 0; s < 2; ++s)
#pragma unroll
        for (int n = 0; n < 4; ++n)
          acc[s][n] = MFMA16(af[s][kk], bf[n][kk], acc[s][n]);
    cur ^= 1;
  }
#undef STAGE_OUT

#pragma unroll
  for (int n = 0; n < 4; ++n) {
    const int gn = colTile + wn * 64 + n * 16 + l16;
    const float bn = bias[gn];
#pragma unroll
    for (int s = 0; s < 2; ++s)
#pragma unroll
      for (int r = 0; r < 4; ++r) {
        const int gm = rowTile + wm * 32 + s * 16 + quad * 4 + r;
        out[(size_t)gm * 1024 + gn] = acc[s][n][r] + bn;
      }
  }
}

// =====================================================================
extern "C" void kernel_launch(void* const* d_in, const int* in_sizes, int n_in,
                              void* d_out, int out_size, void* d_ws, size_t ws_size,
                              hipStream_t stream) {
  (void)in_sizes; (void)n_in; (void)out_size; (void)ws_size;
  const float* x     = (const float*)d_in[0];
  const float* w_qkv = (const float*)d_in[1];
  const float* b_qkv = (const float*)d_in[2];
  const float* w_out = (const float*)d_in[3];
  const float* b_out = (const float*)d_in[4];
  float* out = (float*)d_out;

  u16* xb  = (u16*)d_ws;
  u16* wqb = xb + XN;
  u16* wob = wqb + WQN;
  u16* Qw  = wob + WON;
  u16* Vw  = Qw + (size_t)2 * Hc * Lc * Dc;
  u16* Vtw = Vw + (size_t)2 * Hc * Lc * Dc;
  u16* Aw  = Vtw + (size_t)2 * Hc * Lc * Dc;

  convert_all<<<7168, 256, 0, stream>>>(x, w_qkv, w_out, xb, wqb, wob);
  gemm_qv<<<512, 256, 0, stream>>>(xb, wqb, b_qkv, Qw, Vw, Vtw);
  attn_mfma<<<512, 256, 0, stream>>>(Qw, Vw, Vtw, Aw);
  gemm_out<<<512, 256, 0, stream>>>(Aw, wob, b_out, out);
}

// Round 14
// 242.439 us; speedup vs baseline: 1.0082x; 1.0082x over previous
//
#include <hip/hip_runtime.h>
#include <math.h>

// Problem constants: B=2, L=2048, E=1024, H=16, D=64
constexpr int Lc = 2048, Ec = 1024, Hc = 16, Dc = 64;

typedef __attribute__((ext_vector_type(8))) short bf16x8;
typedef __attribute__((ext_vector_type(4))) float f32x4;
typedef unsigned short u16;
typedef unsigned int u32;

#define MFMA16(a, b, c) __builtin_amdgcn_mfma_f32_16x16x32_bf16(a, b, c, 0, 0, 0)

__device__ inline u16 f2bf(float f) {
  u32 u = __builtin_bit_cast(u32, f);
  u32 r = u + 0x7fff + ((u >> 16) & 1);   // RNE
  return (u16)(r >> 16);
}

__device__ inline void gld16(const void* g, void* l) {
  __builtin_amdgcn_global_load_lds(
      (const __attribute__((address_space(1))) u32*)g,
      (__attribute__((address_space(3))) u32*)l, 16, 0, 0);
}

// =====================================================================
// Prepass: fp32 -> bf16 for x (4M), w_qkv Q+V rows (2M fused), w_out (1M).
// =====================================================================
constexpr size_t XN = (size_t)4096 * 1024;
constexpr size_t WQN = (size_t)2048 * 1024;
constexpr size_t WON = (size_t)1024 * 1024;

__global__ __launch_bounds__(256) void convert_all(
    const float* __restrict__ x, const float* __restrict__ wqkv,
    const float* __restrict__ wout, u16* __restrict__ xb,
    u16* __restrict__ wqb, u16* __restrict__ wob)
{
  const size_t i = ((size_t)blockIdx.x * 256 + threadIdx.x) * 4;
  float4 v;
  u16* dst;
  if (i < XN) {
    v = *(const float4*)(x + i);
    dst = xb + i;
  } else if (i < XN + WQN) {
    const size_t off = i - XN;
    const size_t row = off >> 10, col = off & 1023;
    const size_t srow = row + ((row >> 10) << 10);   // skip K rows of w_qkv
    v = *(const float4*)(wqkv + srow * 1024 + col);
    dst = wqb + off;
  } else {
    const size_t off = i - XN - WQN;
    v = *(const float4*)(wout + off);
    dst = wob + off;
  }
  u16 o0 = f2bf(v.x), o1 = f2bf(v.y), o2 = f2bf(v.z), o3 = f2bf(v.w);
  dst[0] = o0; dst[1] = o1; dst[2] = o2; dst[3] = o3;
}

// =====================================================================
// QV GEMM v7 (bf16 MFMA): M=4096, N=2048 (fused Q|V), K=1024.
// Unchanged from round 10 (BK=64, XOR swizzle, XCD-patch dispatch,
// fused Vt transpose store in epilogue).
// =====================================================================
__global__ __launch_bounds__(256) void gemm_qv(
    const u16* __restrict__ A, const u16* __restrict__ W,
    const float* __restrict__ bqkv, u16* __restrict__ Q, u16* __restrict__ V,
    u16* __restrict__ Vt)
{
  __shared__ __align__(16) u16 As[2][8192];   // 128 rows x 64 u16
  __shared__ __align__(16) u16 Bs[2][8192];
  const int tid = threadIdx.x;
  const int w = tid >> 6, lane = tid & 63;
  const int quad = lane >> 4, l16 = lane & 15;
  const int wm = w >> 1, wn = w & 1;

  // XCD-patch swizzle: grid rows R=32, cols C=16; patches 8x8.
  const int flat = blockIdx.x;
  const int xcd = flat & 7, s64 = flat >> 3;        // s64 in [0,64)
  const int pr = xcd >> 1, pc = xcd & 1;            // 4x2 patch grid
  const int rowTile = (pr * 8 + (s64 >> 3)) * 128;
  const int colTile = (pc * 8 + (s64 & 7)) * 128;

  // staging: dest byte b = tid*16 (+4096*j); row = b>>7 = srow+32j,
  // source element = b ^ ((row&7)<<4)  (row&7 invariant under +32)
  const int srow = tid >> 3;
  const int e = (((tid & 7) * 16) ^ ((srow & 7) << 4)) >> 1;   // u16 in [0,64)
  const u16* Asrc = A + (size_t)(rowTile + srow) * 1024 + e;
  const u16* Bsrc = W + (size_t)(colTile + srow) * 1024 + e;

  f32x4 acc[4][4] = {};

#define STAGE_QV(sb, k0)                                              \
  {                                                                   \
    gld16(Asrc + (k0),             &As[sb][tid * 8]);                 \
    gld16(Asrc + (k0) + 32 * 1024, &As[sb][tid * 8 + 2048]);          \
    gld16(Asrc + (k0) + 64 * 1024, &As[sb][tid * 8 + 4096]);          \
    gld16(Asrc + (k0) + 96 * 1024, &As[sb][tid * 8 + 6144]);          \
    gld16(Bsrc + (k0),             &Bs[sb][tid * 8]);                 \
    gld16(Bsrc + (k0) + 32 * 1024, &Bs[sb][tid * 8 + 2048]);          \
    gld16(Bsrc + (k0) + 64 * 1024, &Bs[sb][tid * 8 + 4096]);          \
    gld16(Bsrc + (k0) + 96 * 1024, &Bs[sb][tid * 8 + 6144]);          \
  }

  STAGE_QV(0, 0);
  int cur = 0;
  for (int k0 = 0; k0 < 1024; k0 += 64) {
    __syncthreads();                       // drains stage(k0) into buf[cur]
    if (k0 + 64 < 1024) STAGE_QV(cur ^ 1, k0 + 64);
    bf16x8 af[4][2], bf[4][2];
#pragma unroll
    for (int s = 0; s < 4; ++s)
#pragma unroll
      for (int kk = 0; kk < 2; ++kk)
        af[s][kk] = *(const bf16x8*)&As[cur][(wm * 64 + s * 16 + l16) * 64 +
                     ((kk * 32 + quad * 8) ^ ((l16 & 7) << 3))];
#pragma unroll
    for (int n = 0; n < 4; ++n)
#pragma unroll
      for (int kk = 0; kk < 2; ++kk)
        bf[n][kk] = *(const bf16x8*)&Bs[cur][(wn * 64 + n * 16 + l16) * 64 +
                     ((kk * 32 + quad * 8) ^ ((l16 & 7) << 3))];
#pragma unroll
    for (int kk = 0; kk < 2; ++kk)
#pragma unroll
      for (int s = 0; s < 4; ++s)
#pragma unroll
        for (int n = 0; n < 4; ++n)
          acc[s][n] = MFMA16(af[s][kk], bf[n][kk], acc[s][n]);
    cur ^= 1;
  }
#undef STAGE_QV

#pragma unroll
  for (int n = 0; n < 4; ++n) {
    const int gn = colTile + wn * 64 + n * 16 + l16;   // fused col 0..2047
    const bool isV = gn >= 1024;
    const float bias = bqkv[gn + (isV ? 1024 : 0)];
    const float scl = isV ? 1.0f : 0.125f;             // fold 1/sqrt(d) into Q
    const int h = (gn & 1023) >> 6, d = gn & 63;
    u16* dst = isV ? V : Q;
#pragma unroll
    for (int s = 0; s < 4; ++s) {
      const int gm0 = rowTile + wm * 64 + s * 16 + quad * 4;
      const int b = gm0 >> 11;             // whole tile within one batch
      ushort4 tv;
#pragma unroll
      for (int r = 0; r < 4; ++r) {
        const int l = (gm0 + r) & 2047;
        const u16 val = f2bf((acc[s][n][r] + bias) * scl);
        dst[(((size_t)(b * Hc + h)) * Lc + l) * Dc + d] = val;
        ((u16*)&tv)[r] = val;
      }
      if (isV) {                           // fused transpose store
        const int l0 = gm0 & 2047;
        *(ushort4*)(Vt + (((size_t)(b * Hc + h)) * Dc + d) * Lc + l0) = tv;
      }
    }
  }
}

// =====================================================================
// Flash attention v6 (bug-faithful: scores = Q.V^T, Q pre-scaled 1/8).
// Register-prefetch: v5 showed traffic is fine (L2-resident, FETCH flat)
// but consume-on-load serializes on ~200-500cyc latency.  v6 keeps the
// global fragment loads but double-buffers them in REGISTERS with
// distance 1: load(setB, t+1) issues before compute(setA, t) -> a full
// tile of compute covers the latency.  No LDS for V/Vt (removes ~65% of
// v3's LDS-pipe load), no __syncthreads (Ps per-wave).  Unroll-by-2
// with named sets (no runtime-indexed reg arrays).
// =====================================================================
constexpr int PSTR = 72;    // Ps row stride (u16)

__device__ inline void load_set(const u16* __restrict__ vbase,
                                const u16* __restrict__ tbase, int kt,
                                bf16x8 bv[4][2], bf16x8 bvt[4][2])
{
#pragma unroll
  for (int nb = 0; nb < 4; ++nb)
#pragma unroll
    for (int kk = 0; kk < 2; ++kk) {
      bv[nb][kk]  = *(const bf16x8*)(vbase + (size_t)(kt + nb * 16) * 64 + kk * 32);
      bvt[nb][kk] = *(const bf16x8*)(tbase + (size_t)nb * 16 * Lc + kt + kk * 32);
    }
}

__device__ inline void attn_half(
    const bf16x8 qf[2], const bf16x8 bv[4][2], const bf16x8 bvt[4][2],
    u16* __restrict__ Ps, f32x4 O[4], float lsum[4],
    int kt, int wq, bool needmask, int quad, int l16)
{
  // ---- S = Q V^T ----
  f32x4 sf[4] = {};
#pragma unroll
  for (int nb = 0; nb < 4; ++nb) {
    sf[nb] = MFMA16(qf[0], bv[nb][0], sf[nb]);
    sf[nb] = MFMA16(qf[1], bv[nb][1], sf[nb]);
  }
  // ---- exp + causal mask + partial row sums + P store ----
#pragma unroll
  for (int nb = 0; nb < 4; ++nb)
#pragma unroll
    for (int r = 0; r < 4; ++r) {
      float p = __expf(sf[nb][r]);        // scores bounded; Q pre-scaled
      if (needmask) {
        const int key = kt + nb * 16 + l16;
        const int qr = wq + quad * 4 + r;
        if (key > qr) p = 0.f;
      }
      lsum[r] += p;
      Ps[(quad * 4 + r) * PSTR + nb * 16 + l16] = f2bf(p);
    }
  // ---- O += P V ----
  bf16x8 pf[2];
#pragma unroll
  for (int kk = 0; kk < 2; ++kk)
    pf[kk] = *(const bf16x8*)&Ps[l16 * PSTR + kk * 32 + quad * 8];
#pragma unroll
  for (int db = 0; db < 4; ++db) {
    O[db] = MFMA16(pf[0], bvt[db][0], O[db]);
    O[db] = MFMA16(pf[1], bvt[db][1], O[db]);
  }
}

__global__ __launch_bounds__(256) void attn_mfma(
    const u16* __restrict__ Q, const u16* __restrict__ V,
    const u16* __restrict__ Vt, u16* __restrict__ outA)
{
  // LDS: only per-wave Ps transpose buffers (lo then hi).  18KB.
  __shared__ __align__(16) u16 PsAll[2 * 4 * 16 * PSTR];
  const int tid = threadIdx.x;
  const int w = tid >> 6, lane = tid & 63;
  const int quad = lane >> 4, l16 = lane & 15;

  // XCD-locality swizzle (hw round-robins linear id across 8 XCDs)
  const int flat = blockIdx.x;
  const int xcd = flat & 7, slot = flat >> 3;
  const int bh = xcd * 4 + (slot >> 4);
  const int xblk = slot & 15;
  const int b = bh >> 4, h = bh & 15;

  const u16* Qb = Q + (size_t)bh * Lc * Dc;
  const u16* Vb = V + (size_t)bh * Lc * Dc;
  const u16* Vtb = Vt + (size_t)bh * Dc * Lc;
  u16* Psl = &PsAll[w * 16 * PSTR];
  u16* Psh = &PsAll[(4 + w) * 16 * PSTR];

  // per-lane fragment base pointers
  const u16* vbase = Vb + (size_t)l16 * 64 + quad * 8;   // + (kt+nb*16)*64 + kk*32
  const u16* tbase = Vtb + (size_t)l16 * Lc + quad * 8;  // + nb*16*Lc + kt + kk*32

  const int qlo = xblk, qhi = 31 - xblk;
  const int nt = qhi + 1;                 // key tiles: union of both halves
  const int wqlo = qlo * 64 + w * 16;
  const int wqhi = qhi * 64 + w * 16;

  // Q fragments for both halves (A-operand)
  bf16x8 qfl[2], qfh[2];
#pragma unroll
  for (int kk = 0; kk < 2; ++kk) {
    qfl[kk] = *(const bf16x8*)(Qb + (size_t)(qlo * 64 + w * 16 + l16) * 64 + kk * 32 + quad * 8);
    qfh[kk] = *(const bf16x8*)(Qb + (size_t)(qhi * 64 + w * 16 + l16) * 64 + kk * 32 + quad * 8);
  }

  f32x4 Ol[4] = {}, Oh[4] = {};
  float lsl[4] = {0.f, 0.f, 0.f, 0.f}, lsh[4] = {0.f, 0.f, 0.f, 0.f};

  // double register sets, distance-1 prefetch
  bf16x8 bvA[4][2], bvtA[4][2], bvB[4][2], bvtB[4][2];
  load_set(vbase, tbase, 0, bvA, bvtA);

  int t = 0;
  for (;;) {
    const int ktA = t * 64;
    if (t + 1 < nt) load_set(vbase, tbase, ktA + 64, bvB, bvtB);
    attn_half(qfh, bvA, bvtA, Psh, Oh, lsh, ktA, wqhi, t == qhi, quad, l16);
    if (t <= qlo)
      attn_half(qfl, bvA, bvtA, Psl, Ol, lsl, ktA, wqlo, t == qlo, quad, l16);
    if (++t >= nt) break;

    const int ktB = t * 64;
    if (t + 1 < nt) load_set(vbase, tbase, ktB + 64, bvA, bvtA);
    attn_half(qfh, bvB, bvtB, Psh, Oh, lsh, ktB, wqhi, t == qhi, quad, l16);
    if (t <= qlo)
      attn_half(qfl, bvB, bvtB, Psl, Ol, lsl, ktB, wqlo, t == qlo, quad, l16);
    if (++t >= nt) break;
  }

  // epilogue: reduce row sums over the 16 lanes, normalize, store
#pragma unroll
  for (int half = 0; half < 2; ++half) {
    const int q0 = half ? qhi * 64 : qlo * 64;
    const f32x4* O = half ? Oh : Ol;
    const float* ls = half ? lsh : lsl;
#pragma unroll
    for (int r = 0; r < 4; ++r) {
      float l = ls[r];
      l += __shfl_xor(l, 1);
      l += __shfl_xor(l, 2);
      l += __shfl_xor(l, 4);
      l += __shfl_xor(l, 8);
      const float inv = 1.f / l;
      const int q = q0 + w * 16 + quad * 4 + r;
      const int orow = h * 128 + (q >> 4);
      const int cbase = (q & 15) << 6;
#pragma unroll
      for (int db = 0; db < 4; ++db)
        outA[((size_t)b * Lc + orow) * Ec + cbase + db * 16 + l16] =
            f2bf(O[db][r] * inv);
    }
  }
}

// =====================================================================
// Out GEMM v6: out[m][n] = sum_k Aw[m][k]*wob[n][k] + b_out[n], fp32 out.
// Unchanged from round 10 (64x128 tile, BK=64, swizzle, XCD-patch).
// =====================================================================
__global__ __launch_bounds__(256) void gemm_out(
    const u16* __restrict__ A, const u16* __restrict__ W,
    const float* __restrict__ bias, float* __restrict__ out)
{
  __shared__ __align__(16) u16 As[2][4096];   // 64 rows x 64 u16
  __shared__ __align__(16) u16 Bs[2][8192];   // 128 rows x 64 u16
  const int tid = threadIdx.x;
  const int w = tid >> 6, lane = tid & 63;
  const int quad = lane >> 4, l16 = lane & 15;
  const int wm = w >> 1, wn = w & 1;          // wm: 2x32 rows, wn: 2x64 cols

  // XCD-patch swizzle: grid rows R=64, cols C=8; xcd owns 8 rows x 8 cols.
  const int flat = blockIdx.x;
  const int xcd = flat & 7, s64 = flat >> 3;        // s64 in [0,64)
  const int rowTile = (xcd * 8 + (s64 >> 3)) * 64;
  const int colTile = (s64 & 7) * 128;

  const int srow = tid >> 3;
  const int e = (((tid & 7) * 16) ^ ((srow & 7) << 4)) >> 1;   // u16 in [0,64)
  const u16* Asrc = A + (size_t)(rowTile + srow) * 1024 + e;
  const u16* Bsrc = W + (size_t)(colTile + srow) * 1024 + e;

  f32x4 acc[2][4] = {};

#define STAGE_OUT(sb, k0)                                             \
  {                                                                   \
    gld16(Asrc + (k0),             &As[sb][tid * 8]);                 \
    gld16(Asrc + (k0) + 32 * 1024, &As[sb][tid * 8 + 2048]);          \
    gld16(Bsrc + (k0),             &Bs[sb][tid * 8]);                 \
    gld16(Bsrc + (k0) + 32 * 1024, &Bs[sb][tid * 8 + 2048]);          \
    gld16(Bsrc + (k0) + 64 * 1024, &Bs[sb][tid * 8 + 4096]);          \
    gld16(Bsrc + (k0) + 96 * 1024, &Bs[sb][tid * 8 + 6144]);          \
  }

  STAGE_OUT(0, 0);
  int cur = 0;
  for (int k0 = 0; k0 < 1024; k0 += 64) {
    __syncthreads();
    if (k0 + 64 < 1024) STAGE_OUT(cur ^ 1, k0 + 64);
    bf16x8 af[2][2], bf[4][2];
#pragma unroll
    for (int s = 0; s < 2; ++s)
#pragma unroll
      for (int kk = 0; kk < 2; ++kk)
        af[s][kk] = *(const bf16x8*)&As[cur][(wm * 32 + s * 16 + l16) * 64 +
                     ((kk * 32 + quad * 8) ^ ((l16 & 7) << 3))];
#pragma unroll
    for (int n = 0; n < 4; ++n)
#pragma unroll
      for (int kk = 0; kk < 2; ++kk)
        bf[n][kk] = *(const bf16x8*)&Bs[cur][(wn * 64 + n * 16 + l16) * 64 +
                     ((kk * 32 + quad * 8) ^ ((l16 & 7) << 3))];
#pragma unroll
    for (int kk = 0; kk < 2; ++kk)
#pragma unroll
      for (int s = 0; s < 2; ++s)
#pragma unroll
        for (int n = 0; n < 4; ++n)
          acc[s][n] = MFMA16(af[s][kk], bf[n][kk], acc[s][n]);
    cur ^= 1;
  }
#undef STAGE_OUT

#pragma unroll
  for (int n = 0; n < 4; ++n) {
    const int gn = colTile + wn * 64 + n * 16 + l16;
    const float bn = bias[gn];
#pragma unroll
    for (int s = 0; s < 2; ++s)
#pragma unroll
      for (int r = 0; r < 4; ++r) {
        const int gm = rowTile + wm * 32 + s * 16 + quad * 4 + r;
        out[(size_t)gm * 1024 + gn] = acc[s][n][r] + bn;
      }
  }
}

// =====================================================================
extern "C" void kernel_launch(void* const* d_in, const int* in_sizes, int n_in,
                              void* d_out, int out_size, void* d_ws, size_t ws_size,
                              hipStream_t stream) {
  (void)in_sizes; (void)n_in; (void)out_size; (void)ws_size;
  const float* x     = (const float*)d_in[0];
  const float* w_qkv = (const float*)d_in[1];
  const float* b_qkv = (const float*)d_in[2];
  const float* w_out = (const float*)d_in[3];
  const float* b_out = (const float*)d_in[4];
  float* out = (float*)d_out;

  u16* xb  = (u16*)d_ws;
  u16* wqb = xb + XN;
  u16* wob = wqb + WQN;
  u16* Qw  = wob + WON;
  u16* Vw  = Qw + (size_t)2 * Hc * Lc * Dc;
  u16* Vtw = Vw + (size_t)2 * Hc * Lc * Dc;
  u16* Aw  = Vtw + (size_t)2 * Hc * Lc * Dc;

  convert_all<<<7168, 256, 0, stream>>>(x, w_qkv, w_out, xb, wqb, wob);
  gemm_qv<<<512, 256, 0, stream>>>(xb, wqb, b_qkv, Qw, Vw, Vtw);
  attn_mfma<<<512, 256, 0, stream>>>(Qw, Vw, Vtw, Aw);
  gemm_out<<<512, 256, 0, stream>>>(Aw, wob, b_out, out);
}

// Round 18
// 185.243 us; speedup vs baseline: 1.3194x; 1.3088x over previous
//
#include <hip/hip_runtime.h>
#include <math.h>

// Problem constants: B=2, L=2048, E=1024, H=16, D=64
constexpr int Lc = 2048, Ec = 1024, Hc = 16, Dc = 64;

typedef __attribute__((ext_vector_type(8))) short bf16x8;
typedef __attribute__((ext_vector_type(4))) float f32x4;
typedef unsigned short u16;
typedef unsigned int u32;

#define MFMA16(a, b, c) __builtin_amdgcn_mfma_f32_16x16x32_bf16(a, b, c, 0, 0, 0)

__device__ inline u16 f2bf(float f) {
  u32 u = __builtin_bit_cast(u32, f);
  u32 r = u + 0x7fff + ((u >> 16) & 1);   // RNE
  return (u16)(r >> 16);
}

__device__ inline void gld16(const void* g, void* l) {
  __builtin_amdgcn_global_load_lds(
      (const __attribute__((address_space(1))) u32*)g,
      (__attribute__((address_space(3))) u32*)l, 16, 0, 0);
}

// =====================================================================
// Prepass: fp32 -> bf16 for x (4M), w_qkv Q+V rows (2M fused), w_out (1M).
// =====================================================================
constexpr size_t XN = (size_t)4096 * 1024;
constexpr size_t WQN = (size_t)2048 * 1024;
constexpr size_t WON = (size_t)1024 * 1024;

__global__ __launch_bounds__(256) void convert_all(
    const float* __restrict__ x, const float* __restrict__ wqkv,
    const float* __restrict__ wout, u16* __restrict__ xb,
    u16* __restrict__ wqb, u16* __restrict__ wob)
{
  const size_t i = ((size_t)blockIdx.x * 256 + threadIdx.x) * 4;
  float4 v;
  u16* dst;
  if (i < XN) {
    v = *(const float4*)(x + i);
    dst = xb + i;
  } else if (i < XN + WQN) {
    const size_t off = i - XN;
    const size_t row = off >> 10, col = off & 1023;
    const size_t srow = row + ((row >> 10) << 10);   // skip K rows of w_qkv
    v = *(const float4*)(wqkv + srow * 1024 + col);
    dst = wqb + off;
  } else {
    const size_t off = i - XN - WQN;
    v = *(const float4*)(wout + off);
    dst = wob + off;
  }
  u16 o0 = f2bf(v.x), o1 = f2bf(v.y), o2 = f2bf(v.z), o3 = f2bf(v.w);
  dst[0] = o0; dst[1] = o1; dst[2] = o2; dst[3] = o3;
}

// =====================================================================
// QV GEMM v7 (bf16 MFMA): M=4096, N=2048 (fused Q|V), K=1024.
// Unchanged from round 10 (BK=64, XOR swizzle, XCD-patch dispatch,
// fused Vt transpose store in epilogue).
// =====================================================================
__global__ __launch_bounds__(256) void gemm_qv(
    const u16* __restrict__ A, const u16* __restrict__ W,
    const float* __restrict__ bqkv, u16* __restrict__ Q, u16* __restrict__ V,
    u16* __restrict__ Vt)
{
  __shared__ __align__(16) u16 As[2][8192];   // 128 rows x 64 u16
  __shared__ __align__(16) u16 Bs[2][8192];
  const int tid = threadIdx.x;
  const int w = tid >> 6, lane = tid & 63;
  const int quad = lane >> 4, l16 = lane & 15;
  const int wm = w >> 1, wn = w & 1;

  // XCD-patch swizzle: grid rows R=32, cols C=16; patches 8x8.
  const int flat = blockIdx.x;
  const int xcd = flat & 7, s64 = flat >> 3;        // s64 in [0,64)
  const int pr = xcd >> 1, pc = xcd & 1;            // 4x2 patch grid
  const int rowTile = (pr * 8 + (s64 >> 3)) * 128;
  const int colTile = (pc * 8 + (s64 & 7)) * 128;

  // staging: dest byte b = tid*16 (+4096*j); row = b>>7 = srow+32j,
  // source element = b ^ ((row&7)<<4)  (row&7 invariant under +32)
  const int srow = tid >> 3;
  const int e = (((tid & 7) * 16) ^ ((srow & 7) << 4)) >> 1;   // u16 in [0,64)
  const u16* Asrc = A + (size_t)(rowTile + srow) * 1024 + e;
  const u16* Bsrc = W + (size_t)(colTile + srow) * 1024 + e;

  f32x4 acc[4][4] = {};

#define STAGE_QV(sb, k0)                                              \
  {                                                                   \
    gld16(Asrc + (k0),             &As[sb][tid * 8]);                 \
    gld16(Asrc + (k0) + 32 * 1024, &As[sb][tid * 8 + 2048]);          \
    gld16(Asrc + (k0) + 64 * 1024, &As[sb][tid * 8 + 4096]);          \
    gld16(Asrc + (k0) + 96 * 1024, &As[sb][tid * 8 + 6144]);          \
    gld16(Bsrc + (k0),             &Bs[sb][tid * 8]);                 \
    gld16(Bsrc + (k0) + 32 * 1024, &Bs[sb][tid * 8 + 2048]);          \
    gld16(Bsrc + (k0) + 64 * 1024, &Bs[sb][tid * 8 + 4096]);          \
    gld16(Bsrc + (k0) + 96 * 1024, &Bs[sb][tid * 8 + 6144]);          \
  }

  STAGE_QV(0, 0);
  int cur = 0;
  for (int k0 = 0; k0 < 1024; k0 += 64) {
    __syncthreads();                       // drains stage(k0) into buf[cur]
    if (k0 + 64 < 1024) STAGE_QV(cur ^ 1, k0 + 64);
    bf16x8 af[4][2], bf[4][2];
#pragma unroll
    for (int s = 0; s < 4; ++s)
#pragma unroll
      for (int kk = 0; kk < 2; ++kk)
        af[s][kk] = *(const bf16x8*)&As[cur][(wm * 64 + s * 16 + l16) * 64 +
                     ((kk * 32 + quad * 8) ^ ((l16 & 7) << 3))];
#pragma unroll
    for (int n = 0; n < 4; ++n)
#pragma unroll
      for (int kk = 0; kk < 2; ++kk)
        bf[n][kk] = *(const bf16x8*)&Bs[cur][(wn * 64 + n * 16 + l16) * 64 +
                     ((kk * 32 + quad * 8) ^ ((l16 & 7) << 3))];
#pragma unroll
    for (int kk = 0; kk < 2; ++kk)
#pragma unroll
      for (int s = 0; s < 4; ++s)
#pragma unroll
        for (int n = 0; n < 4; ++n)
          acc[s][n] = MFMA16(af[s][kk], bf[n][kk], acc[s][n]);
    cur ^= 1;
  }
#undef STAGE_QV

#pragma unroll
  for (int n = 0; n < 4; ++n) {
    const int gn = colTile + wn * 64 + n * 16 + l16;   // fused col 0..2047
    const bool isV = gn >= 1024;
    const float bias = bqkv[gn + (isV ? 1024 : 0)];
    const float scl = isV ? 1.0f : 0.125f;             // fold 1/sqrt(d) into Q
    const int h = (gn & 1023) >> 6, d = gn & 63;
    u16* dst = isV ? V : Q;
#pragma unroll
    for (int s = 0; s < 4; ++s) {
      const int gm0 = rowTile + wm * 64 + s * 16 + quad * 4;
      const int b = gm0 >> 11;             // whole tile within one batch
      ushort4 tv;
#pragma unroll
      for (int r = 0; r < 4; ++r) {
        const int l = (gm0 + r) & 2047;
        const u16 val = f2bf((acc[s][n][r] + bias) * scl);
        dst[(((size_t)(b * Hc + h)) * Lc + l) * Dc + d] = val;
        ((u16*)&tv)[r] = val;
      }
      if (isV) {                           // fused transpose store
        const int l0 = gm0 & 2047;
        *(ushort4*)(Vt + (((size_t)(b * Hc + h)) * Dc + d) * Lc + l0) = tv;
      }
    }
  }
}

// =====================================================================
// Flash attention v7 (bug-faithful: scores = Q.V^T, Q pre-scaled 1/8).
// = proven v3 skeleton (LDS staging via gld16, dbuf, XOR swizzle, one
// barrier per key-tile) with the half-sharing extended 2 -> 4:
// block p handles q-tiles {p, 15-p, 16+p, 31-p} -- every block does
// EXACTLY 66 MFMA-units (balance preserved, unlike v4), and the same
// bv/bvt fragment reads feed up to 4 halves (2x less LDS-read + 2x
// fewer staged tiles than v3).  Grid 256 (8 p x 32 bh), 1 block/CU.
// One Ps buffer per wave (write->read is wave-local within a half).
// =====================================================================
constexpr int PSTR = 72;    // Ps row stride (u16)

__device__ inline void attn_half(
    const bf16x8 qf[2], const bf16x8 bv[4][2], const bf16x8 bvt[4][2],
    u16* __restrict__ Ps, f32x4 O[4], float lsum[4],
    int kt, int wq, bool needmask, int quad, int l16)
{
  // ---- S = Q V^T ----
  f32x4 sf[4] = {};
#pragma unroll
  for (int nb = 0; nb < 4; ++nb) {
    sf[nb] = MFMA16(qf[0], bv[nb][0], sf[nb]);
    sf[nb] = MFMA16(qf[1], bv[nb][1], sf[nb]);
  }
  // ---- exp + causal mask + partial row sums + P store ----
#pragma unroll
  for (int nb = 0; nb < 4; ++nb)
#pragma unroll
    for (int r = 0; r < 4; ++r) {
      float p = __expf(sf[nb][r]);        // scores bounded; Q pre-scaled
      if (needmask) {
        const int key = kt + nb * 16 + l16;
        const int qr = wq + quad * 4 + r;
        if (key > qr) p = 0.f;
      }
      lsum[r] += p;
      Ps[(quad * 4 + r) * PSTR + nb * 16 + l16] = f2bf(p);
    }
  // ---- O += P V ----
  bf16x8 pf[2];
#pragma unroll
  for (int kk = 0; kk < 2; ++kk)
    pf[kk] = *(const bf16x8*)&Ps[l16 * PSTR + kk * 32 + quad * 8];
#pragma unroll
  for (int db = 0; db < 4; ++db) {
    O[db] = MFMA16(pf[0], bvt[db][0], O[db]);
    O[db] = MFMA16(pf[1], bvt[db][1], O[db]);
  }
}

__device__ inline void epi_half(
    const f32x4 O[4], const float ls[4], int q0, int w, int quad, int l16,
    int b, int h, u16* __restrict__ outA)
{
#pragma unroll
  for (int r = 0; r < 4; ++r) {
    float l = ls[r];
    l += __shfl_xor(l, 1);
    l += __shfl_xor(l, 2);
    l += __shfl_xor(l, 4);
    l += __shfl_xor(l, 8);
    const float inv = 1.f / l;
    const int q = q0 + w * 16 + quad * 4 + r;
    const int orow = h * 128 + (q >> 4);
    const int cbase = (q & 15) << 6;
#pragma unroll
    for (int db = 0; db < 4; ++db)
      outA[((size_t)b * Lc + orow) * Ec + cbase + db * 16 + l16] =
          f2bf(O[db][r] * inv);
  }
}

__global__ __launch_bounds__(256) void attn_mfma(
    const u16* __restrict__ Q, const u16* __restrict__ V,
    const u16* __restrict__ Vt, u16* __restrict__ outA)
{
  // [0,8192) u16: Vs dbuf; [8192,16384): VsT dbuf; [16384,..): per-wave Ps.
  __shared__ __align__(16) u16 lds[2 * 4096 + 2 * 4096 + 4 * 16 * PSTR];
  const int tid = threadIdx.x;
  const int w = tid >> 6, lane = tid & 63;
  const int quad = lane >> 4, l16 = lane & 15;

  // XCD-locality: grid 256 = 8 xcd x (4 bh x 8 p); all 8 p-blocks of one
  // bh on ONE XCD (1MB working set << 4MB L2).
  const int flat = blockIdx.x;
  const int xcd = flat & 7, slot = flat >> 3;       // slot 0..31
  const int bh = xcd * 4 + (slot >> 3);
  const int p = slot & 7;
  const int b = bh >> 4, h = bh & 15;

  const u16* Qb = Q + (size_t)bh * Lc * Dc;
  const u16* Vb = V + (size_t)bh * Lc * Dc;
  const u16* Vtb = Vt + (size_t)bh * Dc * Lc;
  u16* Ps = &lds[16384 + w * 16 * PSTR];

  // staging: LDS byte b (linear) holds tile byte b ^ ((b>>7&7)<<4)
  // -> pre-swizzle the GLOBAL source address.
  const int b1 = tid * 16, b2 = b1 + 4096;
  const int e1 = (b1 ^ (((b1 >> 7) & 7) << 4)) >> 1;   // u16 offset in tile
  const int e2 = (b2 ^ (((b2 >> 7) & 7) << 4)) >> 1;
  const u16* vs1 = Vb + e1;                            // + kt*64 per tile
  const u16* vs2 = Vb + e2;
  const u16* ts1 = Vtb + (size_t)(e1 >> 6) * Lc + (e1 & 63);  // + kt per tile
  const u16* ts2 = Vtb + (size_t)(e2 >> 6) * Lc + (e2 & 63);

  // swizzled LDS read offsets (u16 units): row = i*16+l16, col = kk*32+quad*8
  int roff[4][2];
#pragma unroll
  for (int i = 0; i < 4; ++i)
#pragma unroll
    for (int kk = 0; kk < 2; ++kk) {
      const int byte = ((i * 16 + l16) << 7) + kk * 64 + quad * 16;
      roff[i][kk] = (byte ^ ((l16 & 7) << 4)) >> 1;
    }

  // balanced quad of q-tiles: units (p+1)+(16-p)+(17+p)+(32-p) = 66 always
  const int q1 = p, q2 = 15 - p, q3 = 16 + p, q4 = 31 - p;
  const int nt = q4 + 1;                  // staged key tiles: 25..32
  const int wq1 = q1 * 64 + w * 16, wq2 = q2 * 64 + w * 16;
  const int wq3 = q3 * 64 + w * 16, wq4 = q4 * 64 + w * 16;

  // Q fragments for the four halves (A-operand)
  bf16x8 qf1[2], qf2[2], qf3[2], qf4[2];
#pragma unroll
  for (int kk = 0; kk < 2; ++kk) {
    qf1[kk] = *(const bf16x8*)(Qb + (size_t)(wq1 + l16) * 64 + kk * 32 + quad * 8);
    qf2[kk] = *(const bf16x8*)(Qb + (size_t)(wq2 + l16) * 64 + kk * 32 + quad * 8);
    qf3[kk] = *(const bf16x8*)(Qb + (size_t)(wq3 + l16) * 64 + kk * 32 + quad * 8);
    qf4[kk] = *(const bf16x8*)(Qb + (size_t)(wq4 + l16) * 64 + kk * 32 + quad * 8);
  }

  f32x4 O1[4] = {}, O2[4] = {}, O3[4] = {}, O4[4] = {};
  float ls1[4] = {}, ls2[4] = {}, ls3[4] = {}, ls4[4] = {};

  // prologue: stage tile 0 into buffer 0
  gld16(vs1, &lds[tid * 8]);
  gld16(vs2, &lds[2048 + tid * 8]);
  gld16(ts1, &lds[8192 + tid * 8]);
  gld16(ts2, &lds[8192 + 2048 + tid * 8]);

  int cur = 0;
  for (int t = 0; t < nt; ++t) {
    const int kt = t * 64;
    __syncthreads();                      // drains stage(t) into buf[cur]
    if (t + 1 < nt) {                     // next tile in flight during compute
      const int sb = cur ^ 1, nk = kt + 64;
      gld16(vs1 + (size_t)nk * 64, &lds[sb * 4096 + tid * 8]);
      gld16(vs2 + (size_t)nk * 64, &lds[sb * 4096 + 2048 + tid * 8]);
      gld16(ts1 + nk, &lds[8192 + sb * 4096 + tid * 8]);
      gld16(ts2 + nk, &lds[8192 + sb * 4096 + 2048 + tid * 8]);
    }
    const u16* VsB = &lds[cur * 4096];
    const u16* VtB = &lds[8192 + cur * 4096];

    // B-operand fragments: loaded ONCE, shared by up to 4 halves
    bf16x8 bv[4][2], bvt[4][2];
#pragma unroll
    for (int nb = 0; nb < 4; ++nb)
#pragma unroll
      for (int kk = 0; kk < 2; ++kk) {
        bv[nb][kk] = *(const bf16x8*)(VsB + roff[nb][kk]);
        bvt[nb][kk] = *(const bf16x8*)(VtB + roff[nb][kk]);
      }

    // q4 computes every tile; others drop out as t grows (wave-uniform)
    attn_half(qf4, bv, bvt, Ps, O4, ls4, kt, wq4, t == q4, quad, l16);
    if (t <= q3) attn_half(qf3, bv, bvt, Ps, O3, ls3, kt, wq3, t == q3, quad, l16);
    if (t <= q2) attn_half(qf2, bv, bvt, Ps, O2, ls2, kt, wq2, t == q2, quad, l16);
    if (t <= q1) attn_half(qf1, bv, bvt, Ps, O1, ls1, kt, wq1, t == q1, quad, l16);
    cur ^= 1;
  }

  // epilogue: reduce row sums, normalize, store (4 halves)
  epi_half(O1, ls1, q1 * 64, w, quad, l16, b, h, outA);
  epi_half(O2, ls2, q2 * 64, w, quad, l16, b, h, outA);
  epi_half(O3, ls3, q3 * 64, w, quad, l16, b, h, outA);
  epi_half(O4, ls4, q4 * 64, w, quad, l16, b, h, outA);
}

// =====================================================================
// Out GEMM v6: out[m][n] = sum_k Aw[m][k]*wob[n][k] + b_out[n], fp32 out.
// Unchanged from round 10 (64x128 tile, BK=64, swizzle, XCD-patch).
// =====================================================================
__global__ __launch_bounds__(256) void gemm_out(
    const u16* __restrict__ A, const u16* __restrict__ W,
    const float* __restrict__ bias, float* __restrict__ out)
{
  __shared__ __align__(16) u16 As[2][4096];   // 64 rows x 64 u16
  __shared__ __align__(16) u16 Bs[2][8192];   // 128 rows x 64 u16
  const int tid = threadIdx.x;
  const int w = tid >> 6, lane = tid & 63;
  const int quad = lane >> 4, l16 = lane & 15;
  const int wm = w >> 1, wn = w & 1;          // wm: 2x32 rows, wn: 2x64 cols

  // XCD-patch swizzle: grid rows R=64, cols C=8; xcd owns 8 rows x 8 cols.
  const int flat = blockIdx.x;
  const int xcd = flat & 7, s64 = flat >> 3;        // s64 in [0,64)
  const int rowTile = (xcd * 8 + (s64 >> 3)) * 64;
  const int colTile = (s64 & 7) * 128;

  const int srow = tid >> 3;
  const int e = (((tid & 7) * 16) ^ ((srow & 7) << 4)) >> 1;   // u16 in [0,64)
  const u16* Asrc = A + (size_t)(rowTile + srow) * 1024 + e;
  const u16* Bsrc = W + (size_t)(colTile + srow) * 1024 + e;

  f32x4 acc[2][4] = {};

#define STAGE_OUT(sb, k0)                                             \
  {                                                                   \
    gld16(Asrc + (k0),             &As[sb][tid * 8]);                 \
    gld16(Asrc + (k0) + 32 * 1024, &As[sb][tid * 8 + 2048]);          \
    gld16(Bsrc + (k0),             &Bs[sb][tid * 8]);                 \
    gld16(Bsrc + (k0) + 32 * 1024, &Bs[sb][tid * 8 + 2048]);          \
    gld16(Bsrc + (k0) + 64 * 1024, &Bs[sb][tid * 8 + 4096]);          \
    gld16(Bsrc + (k0) + 96 * 1024, &Bs[sb][tid * 8 + 6144]);          \
  }

  STAGE_OUT(0, 0);
  int cur = 0;
  for (int k0 = 0; k0 < 1024; k0 += 64) {
    __syncthreads();
    if (k0 + 64 < 1024) STAGE_OUT(cur ^ 1, k0 + 64);
    bf16x8 af[2][2], bf[4][2];
#pragma unroll
    for (int s = 0; s < 2; ++s)
#pragma unroll
      for (int kk = 0; kk < 2; ++kk)
        af[s][kk] = *(const bf16x8*)&As[cur][(wm * 32 + s * 16 + l16) * 64 +
                     ((kk * 32 + quad * 8) ^ ((l16 & 7) << 3))];
#pragma unroll
    for (int n = 0; n < 4; ++n)
#pragma unroll
      for (int kk = 0; kk < 2; ++kk)
        bf[n][kk] = *(const bf16x8*)&Bs[cur][(wn * 64 + n * 16 + l16) * 64 +
                     ((kk * 32 + quad * 8) ^ ((l16 & 7) << 3))];
#pragma unroll
    for (int kk = 0; kk < 2; ++kk)
#pragma unroll
      for (int s = 0; s < 2; ++s)
#pragma unroll
        for (int n = 0; n < 4; ++n)
          acc[s][n] = MFMA16(af[s][kk], bf[n][kk], acc[s][n]);
    cur ^= 1;
  }
#undef STAGE_OUT

#pragma unroll
  for (int n = 0; n < 4; ++n) {
    const int gn = colTile + wn * 64 + n * 16 + l16;
    const float bn = bias[gn];
#pragma unroll
    for (int s = 0; s < 2; ++s)
#pragma unroll
      for (int r = 0; r < 4; ++r) {
        const int gm = rowTile + wm * 32 + s * 16 + quad * 4 + r;
        out[(size_t)gm * 1024 + gn] = acc[s][n][r] + bn;
      }
  }
}

// =====================================================================
extern "C" void kernel_launch(void* const* d_in, const int* in_sizes, int n_in,
                              void* d_out, int out_size, void* d_ws, size_t ws_size,
                              hipStream_t stream) {
  (void)in_sizes; (void)n_in; (void)out_size; (void)ws_size;
  const float* x     = (const float*)d_in[0];
  const float* w_qkv = (const float*)d_in[1];
  const float* b_qkv = (const float*)d_in[2];
  const float* w_out = (const float*)d_in[3];
  const float* b_out = (const float*)d_in[4];
  float* out = (float*)d_out;

  u16* xb  = (u16*)d_ws;
  u16* wqb = xb + XN;
  u16* wob = wqb + WQN;
  u16* Qw  = wob + WON;
  u16* Vw  = Qw + (size_t)2 * Hc * Lc * Dc;
  u16* Vtw = Vw + (size_t)2 * Hc * Lc * Dc;
  u16* Aw  = Vtw + (size_t)2 * Hc * Lc * Dc;

  convert_all<<<7168, 256, 0, stream>>>(x, w_qkv, w_out, xb, wqb, wob);
  gemm_qv<<<512, 256, 0, stream>>>(xb, wqb, b_qkv, Qw, Vw, Vtw);
  attn_mfma<<<256, 256, 0, stream>>>(Qw, Vw, Vtw, Aw);
  gemm_out<<<512, 256, 0, stream>>>(Aw, wob, b_out, out);
}

// Round 20
// 173.162 us; speedup vs baseline: 1.4115x; 1.0698x over previous
//
#include <hip/hip_runtime.h>
#include <math.h>

// Problem constants: B=2, L=2048, E=1024, H=16, D=64
constexpr int Lc = 2048, Ec = 1024, Hc = 16, Dc = 64;

typedef __attribute__((ext_vector_type(8))) short bf16x8;
typedef __attribute__((ext_vector_type(4))) float f32x4;
typedef unsigned short u16;
typedef unsigned int u32;

#define MFMA16(a, b, c) __builtin_amdgcn_mfma_f32_16x16x32_bf16(a, b, c, 0, 0, 0)

__device__ inline u16 f2bf(float f) {
  u32 u = __builtin_bit_cast(u32, f);
  u32 r = u + 0x7fff + ((u >> 16) & 1);   // RNE
  return (u16)(r >> 16);
}

__device__ inline void gld16(const void* g, void* l) {
  __builtin_amdgcn_global_load_lds(
      (const __attribute__((address_space(1))) u32*)g,
      (__attribute__((address_space(3))) u32*)l, 16, 0, 0);
}

// =====================================================================
// Prepass: fp32 -> bf16 for x (4M), w_qkv Q+V rows (2M fused), w_out (1M).
// =====================================================================
constexpr size_t XN = (size_t)4096 * 1024;
constexpr size_t WQN = (size_t)2048 * 1024;
constexpr size_t WON = (size_t)1024 * 1024;

__global__ __launch_bounds__(256) void convert_all(
    const float* __restrict__ x, const float* __restrict__ wqkv,
    const float* __restrict__ wout, u16* __restrict__ xb,
    u16* __restrict__ wqb, u16* __restrict__ wob)
{
  const size_t i = ((size_t)blockIdx.x * 256 + threadIdx.x) * 4;
  float4 v;
  u16* dst;
  if (i < XN) {
    v = *(const float4*)(x + i);
    dst = xb + i;
  } else if (i < XN + WQN) {
    const size_t off = i - XN;
    const size_t row = off >> 10, col = off & 1023;
    const size_t srow = row + ((row >> 10) << 10);   // skip K rows of w_qkv
    v = *(const float4*)(wqkv + srow * 1024 + col);
    dst = wqb + off;
  } else {
    const size_t off = i - XN - WQN;
    v = *(const float4*)(wout + off);
    dst = wob + off;
  }
  u16 o0 = f2bf(v.x), o1 = f2bf(v.y), o2 = f2bf(v.z), o3 = f2bf(v.w);
  dst[0] = o0; dst[1] = o1; dst[2] = o2; dst[3] = o3;
}

// =====================================================================
// QV GEMM v7 (bf16 MFMA): M=4096, N=2048 (fused Q|V), K=1024.
// Unchanged from round 10 (BK=64, XOR swizzle, XCD-patch dispatch,
// fused Vt transpose store in epilogue).
// =====================================================================
__global__ __launch_bounds__(256) void gemm_qv(
    const u16* __restrict__ A, const u16* __restrict__ W,
    const float* __restrict__ bqkv, u16* __restrict__ Q, u16* __restrict__ V,
    u16* __restrict__ Vt)
{
  __shared__ __align__(16) u16 As[2][8192];   // 128 rows x 64 u16
  __shared__ __align__(16) u16 Bs[2][8192];
  const int tid = threadIdx.x;
  const int w = tid >> 6, lane = tid & 63;
  const int quad = lane >> 4, l16 = lane & 15;
  const int wm = w >> 1, wn = w & 1;

  // XCD-patch swizzle: grid rows R=32, cols C=16; patches 8x8.
  const int flat = blockIdx.x;
  const int xcd = flat & 7, s64 = flat >> 3;        // s64 in [0,64)
  const int pr = xcd >> 1, pc = xcd & 1;            // 4x2 patch grid
  const int rowTile = (pr * 8 + (s64 >> 3)) * 128;
  const int colTile = (pc * 8 + (s64 & 7)) * 128;

  // staging: dest byte b = tid*16 (+4096*j); row = b>>7 = srow+32j,
  // source element = b ^ ((row&7)<<4)  (row&7 invariant under +32)
  const int srow = tid >> 3;
  const int e = (((tid & 7) * 16) ^ ((srow & 7) << 4)) >> 1;   // u16 in [0,64)
  const u16* Asrc = A + (size_t)(rowTile + srow) * 1024 + e;
  const u16* Bsrc = W + (size_t)(colTile + srow) * 1024 + e;

  f32x4 acc[4][4] = {};

#define STAGE_QV(sb, k0)                                              \
  {                                                                   \
    gld16(Asrc + (k0),             &As[sb][tid * 8]);                 \
    gld16(Asrc + (k0) + 32 * 1024, &As[sb][tid * 8 + 2048]);          \
    gld16(Asrc + (k0) + 64 * 1024, &As[sb][tid * 8 + 4096]);          \
    gld16(Asrc + (k0) + 96 * 1024, &As[sb][tid * 8 + 6144]);          \
    gld16(Bsrc + (k0),             &Bs[sb][tid * 8]);                 \
    gld16(Bsrc + (k0) + 32 * 1024, &Bs[sb][tid * 8 + 2048]);          \
    gld16(Bsrc + (k0) + 64 * 1024, &Bs[sb][tid * 8 + 4096]);          \
    gld16(Bsrc + (k0) + 96 * 1024, &Bs[sb][tid * 8 + 6144]);          \
  }

  STAGE_QV(0, 0);
  int cur = 0;
  for (int k0 = 0; k0 < 1024; k0 += 64) {
    __syncthreads();                       // drains stage(k0) into buf[cur]
    if (k0 + 64 < 1024) STAGE_QV(cur ^ 1, k0 + 64);
    bf16x8 af[4][2], bf[4][2];
#pragma unroll
    for (int s = 0; s < 4; ++s)
#pragma unroll
      for (int kk = 0; kk < 2; ++kk)
        af[s][kk] = *(const bf16x8*)&As[cur][(wm * 64 + s * 16 + l16) * 64 +
                     ((kk * 32 + quad * 8) ^ ((l16 & 7) << 3))];
#pragma unroll
    for (int n = 0; n < 4; ++n)
#pragma unroll
      for (int kk = 0; kk < 2; ++kk)
        bf[n][kk] = *(const bf16x8*)&Bs[cur][(wn * 64 + n * 16 + l16) * 64 +
                     ((kk * 32 + quad * 8) ^ ((l16 & 7) << 3))];
#pragma unroll
    for (int kk = 0; kk < 2; ++kk)
#pragma unroll
      for (int s = 0; s < 4; ++s)
#pragma unroll
        for (int n = 0; n < 4; ++n)
          acc[s][n] = MFMA16(af[s][kk], bf[n][kk], acc[s][n]);
    cur ^= 1;
  }
#undef STAGE_QV

#pragma unroll
  for (int n = 0; n < 4; ++n) {
    const int gn = colTile + wn * 64 + n * 16 + l16;   // fused col 0..2047
    const bool isV = gn >= 1024;
    const float bias = bqkv[gn + (isV ? 1024 : 0)];
    const float scl = isV ? 1.0f : 0.125f;             // fold 1/sqrt(d) into Q
    const int h = (gn & 1023) >> 6, d = gn & 63;
    u16* dst = isV ? V : Q;
#pragma unroll
    for (int s = 0; s < 4; ++s) {
      const int gm0 = rowTile + wm * 64 + s * 16 + quad * 4;
      const int b = gm0 >> 11;             // whole tile within one batch
      ushort4 tv;
#pragma unroll
      for (int r = 0; r < 4; ++r) {
        const int l = (gm0 + r) & 2047;
        const u16 val = f2bf((acc[s][n][r] + bias) * scl);
        dst[(((size_t)(b * Hc + h)) * Lc + l) * Dc + d] = val;
        ((u16*)&tv)[r] = val;
      }
      if (isV) {                           // fused transpose store
        const int l0 = gm0 & 2047;
        *(ushort4*)(Vt + (((size_t)(b * Hc + h)) * Dc + d) * Lc + l0) = tv;
      }
    }
  }
}

// =====================================================================
// Flash attention v3r (bug-faithful: scores = Q.V^T, Q pre-scaled 1/8).
// REVERT to the proven round-10 structure (48.3-48.5 us across 3 builds):
// lo/hi q-tile fusion {p, 31-p}, grid 512 (2 blocks/CU -- the residency
// that v7's 4-way sharing destroyed), LDS staging via gld16 + dbuf +
// XOR swizzle, one barrier per key-tile.  NEW (single variable): T5
// s_setprio(1) around the MFMA clusters -- 2 independent blocks/CU are
// at different phases (one staging, one computing), the role diversity
// setprio needs (m191: +4-7% attn; pure hint, zero correctness risk).
// =====================================================================
constexpr int PSTR = 72;    // Ps row stride (u16)

__device__ inline void attn_half(
    const bf16x8 qf[2], const bf16x8 bv[4][2], const bf16x8 bvt[4][2],
    u16* __restrict__ Ps, f32x4 O[4], float lsum[4],
    int kt, int wq, bool needmask, int quad, int l16)
{
  // ---- S = Q V^T ----
  f32x4 sf[4] = {};
  __builtin_amdgcn_s_setprio(1);
#pragma unroll
  for (int nb = 0; nb < 4; ++nb) {
    sf[nb] = MFMA16(qf[0], bv[nb][0], sf[nb]);
    sf[nb] = MFMA16(qf[1], bv[nb][1], sf[nb]);
  }
  __builtin_amdgcn_s_setprio(0);
  // ---- exp + causal mask + partial row sums + P store ----
#pragma unroll
  for (int nb = 0; nb < 4; ++nb)
#pragma unroll
    for (int r = 0; r < 4; ++r) {
      float p = __expf(sf[nb][r]);        // scores bounded; Q pre-scaled
      if (needmask) {
        const int key = kt + nb * 16 + l16;
        const int qr = wq + quad * 4 + r;
        if (key > qr) p = 0.f;
      }
      lsum[r] += p;
      Ps[(quad * 4 + r) * PSTR + nb * 16 + l16] = f2bf(p);
    }
  // ---- O += P V ----
  bf16x8 pf[2];
#pragma unroll
  for (int kk = 0; kk < 2; ++kk)
    pf[kk] = *(const bf16x8*)&Ps[l16 * PSTR + kk * 32 + quad * 8];
  __builtin_amdgcn_s_setprio(1);
#pragma unroll
  for (int db = 0; db < 4; ++db) {
    O[db] = MFMA16(pf[0], bvt[db][0], O[db]);
    O[db] = MFMA16(pf[1], bvt[db][1], O[db]);
  }
  __builtin_amdgcn_s_setprio(0);
}

__global__ __launch_bounds__(256) void attn_mfma(
    const u16* __restrict__ Q, const u16* __restrict__ V,
    const u16* __restrict__ Vt, u16* __restrict__ outA)
{
  // [0..8191] u16: Vs double buffer; [8192..16383]: VsT double buffer;
  // [16384..]: per-wave Ps, lo then hi.
  __shared__ __align__(16) u16 lds[2 * 4096 + 2 * 4096 + 2 * 4 * 16 * PSTR];
  const int tid = threadIdx.x;
  const int w = tid >> 6, lane = tid & 63;
  const int quad = lane >> 4, l16 = lane & 15;

  // XCD-locality swizzle (hw round-robins linear id across 8 XCDs)
  const int flat = blockIdx.x;
  const int xcd = flat & 7, slot = flat >> 3;
  const int bh = xcd * 4 + (slot >> 4);
  const int xblk = slot & 15;
  const int b = bh >> 4, h = bh & 15;

  const u16* Qb = Q + (size_t)bh * Lc * Dc;
  const u16* Vb = V + (size_t)bh * Lc * Dc;
  const u16* Vtb = Vt + (size_t)bh * Dc * Lc;
  u16* Psl = &lds[16384 + w * 16 * PSTR];
  u16* Psh = &lds[16384 + (4 + w) * 16 * PSTR];

  // staging: LDS byte b (linear) holds tile byte b ^ ((b>>7&7)<<4)
  // -> pre-swizzle the GLOBAL source address.
  const int b1 = tid * 16, b2 = b1 + 4096;
  const int e1 = (b1 ^ (((b1 >> 7) & 7) << 4)) >> 1;   // u16 offset in tile
  const int e2 = (b2 ^ (((b2 >> 7) & 7) << 4)) >> 1;
  const u16* vs1 = Vb + e1;                            // + kt*64 per tile
  const u16* vs2 = Vb + e2;
  const u16* ts1 = Vtb + (size_t)(e1 >> 6) * Lc + (e1 & 63);  // + kt per tile
  const u16* ts2 = Vtb + (size_t)(e2 >> 6) * Lc + (e2 & 63);

  // swizzled LDS read offsets (u16 units): row = i*16+l16, col = kk*32+quad*8
  int roff[4][2];
#pragma unroll
  for (int i = 0; i < 4; ++i)
#pragma unroll
    for (int kk = 0; kk < 2; ++kk) {
      const int byte = ((i * 16 + l16) << 7) + kk * 64 + quad * 16;
      roff[i][kk] = (byte ^ ((l16 & 7) << 4)) >> 1;
    }

  const int qlo = xblk, qhi = 31 - xblk;
  const int nt = qhi + 1;                 // staged key tiles: union of halves
  const int wqlo = qlo * 64 + w * 16;
  const int wqhi = qhi * 64 + w * 16;

  // Q fragments for both halves (A-operand)
  bf16x8 qfl[2], qfh[2];
#pragma unroll
  for (int kk = 0; kk < 2; ++kk) {
    qfl[kk] = *(const bf16x8*)(Qb + (size_t)(qlo * 64 + w * 16 + l16) * 64 + kk * 32 + quad * 8);
    qfh[kk] = *(const bf16x8*)(Qb + (size_t)(qhi * 64 + w * 16 + l16) * 64 + kk * 32 + quad * 8);
  }

  f32x4 Ol[4] = {}, Oh[4] = {};
  float lsl[4] = {0.f, 0.f, 0.f, 0.f}, lsh[4] = {0.f, 0.f, 0.f, 0.f};

  // prologue: stage tile 0 into buffer 0
  gld16(vs1, &lds[tid * 8]);
  gld16(vs2, &lds[2048 + tid * 8]);
  gld16(ts1, &lds[8192 + tid * 8]);
  gld16(ts2, &lds[8192 + 2048 + tid * 8]);

  int cur = 0;
  for (int t = 0; t < nt; ++t) {
    const int kt = t * 64;
    __syncthreads();                      // drains stage(t) into buf[cur]
    if (t + 1 < nt) {                     // next tile in flight during compute
      const int sb = cur ^ 1, nk = kt + 64;
      gld16(vs1 + (size_t)nk * 64, &lds[sb * 4096 + tid * 8]);
      gld16(vs2 + (size_t)nk * 64, &lds[sb * 4096 + 2048 + tid * 8]);
      gld16(ts1 + nk, &lds[8192 + sb * 4096 + tid * 8]);
      gld16(ts2 + nk, &lds[8192 + sb * 4096 + 2048 + tid * 8]);
    }
    const u16* VsB = &lds[cur * 4096];
    const u16* VtB = &lds[8192 + cur * 4096];

    // B-operand fragments: loaded ONCE, shared by both halves
    bf16x8 bv[4][2], bvt[4][2];
#pragma unroll
    for (int nb = 0; nb < 4; ++nb)
#pragma unroll
      for (int kk = 0; kk < 2; ++kk) {
        bv[nb][kk] = *(const bf16x8*)(VsB + roff[nb][kk]);
        bvt[nb][kk] = *(const bf16x8*)(VtB + roff[nb][kk]);
      }

    // hi half computes every tile; mask only on its diagonal tile
    attn_half(qfh, bv, bvt, Psh, Oh, lsh, kt, wqhi, t == qhi, quad, l16);
    if (t <= qlo)                         // wave-uniform gate
      attn_half(qfl, bv, bvt, Psl, Ol, lsl, kt, wqlo, t == qlo, quad, l16);
    cur ^= 1;
  }

  // epilogue: reduce row sums over the 16 lanes, normalize, store
#pragma unroll
  for (int half = 0; half < 2; ++half) {
    const int q0 = half ? qhi * 64 : qlo * 64;
    const f32x4* O = half ? Oh : Ol;
    const float* ls = half ? lsh : lsl;
#pragma unroll
    for (int r = 0; r < 4; ++r) {
      float l = ls[r];
      l += __shfl_xor(l, 1);
      l += __shfl_xor(l, 2);
      l += __shfl_xor(l, 4);
      l += __shfl_xor(l, 8);
      const float inv = 1.f / l;
      const int q = q0 + w * 16 + quad * 4 + r;
      const int orow = h * 128 + (q >> 4);
      const int cbase = (q & 15) << 6;
#pragma unroll
      for (int db = 0; db < 4; ++db)
        outA[((size_t)b * Lc + orow) * Ec + cbase + db * 16 + l16] =
            f2bf(O[db][r] * inv);
    }
  }
}

// =====================================================================
// Out GEMM v6: out[m][n] = sum_k Aw[m][k]*wob[n][k] + b_out[n], fp32 out.
// Unchanged from round 10 (64x128 tile, BK=64, swizzle, XCD-patch).
// =====================================================================
__global__ __launch_bounds__(256) void gemm_out(
    const u16* __restrict__ A, const u16* __restrict__ W,
    const float* __restrict__ bias, float* __restrict__ out)
{
  __shared__ __align__(16) u16 As[2][4096];   // 64 rows x 64 u16
  __shared__ __align__(16) u16 Bs[2][8192];   // 128 rows x 64 u16
  const int tid = threadIdx.x;
  const int w = tid >> 6, lane = tid & 63;
  const int quad = lane >> 4, l16 = lane & 15;
  const int wm = w >> 1, wn = w & 1;          // wm: 2x32 rows, wn: 2x64 cols

  // XCD-patch swizzle: grid rows R=64, cols C=8; xcd owns 8 rows x 8 cols.
  const int flat = blockIdx.x;
  const int xcd = flat & 7, s64 = flat >> 3;        // s64 in [0,64)
  const int rowTile = (xcd * 8 + (s64 >> 3)) * 64;
  const int colTile = (s64 & 7) * 128;

  const int srow = tid >> 3;
  const int e = (((tid & 7) * 16) ^ ((srow & 7) << 4)) >> 1;   // u16 in [0,64)
  const u16* Asrc = A + (size_t)(rowTile + srow) * 1024 + e;
  const u16* Bsrc = W + (size_t)(colTile + srow) * 1024 + e;

  f32x4 acc[2][4] = {};

#define STAGE_OUT(sb, k0)                                             \
  {                                                                   \
    gld16(Asrc + (k0),             &As[sb][tid * 8]);                 \
    gld16(Asrc + (k0) + 32 * 1024, &As[sb][tid * 8 + 2048]);          \
    gld16(Bsrc + (k0),             &Bs[sb][tid * 8]);                 \
    gld16(Bsrc + (k0) + 32 * 1024, &Bs[sb][tid * 8 + 2048]);          \
    gld16(Bsrc + (k0) + 64 * 1024, &Bs[sb][tid * 8 + 4096]);          \
    gld16(Bsrc + (k0) + 96 * 1024, &Bs[sb][tid * 8 + 6144]);          \
  }

  STAGE_OUT(0, 0);
  int cur = 0;
  for (int k0 = 0; k0 < 1024; k0 += 64) {
    __syncthreads();
    if (k0 + 64 < 1024) STAGE_OUT(cur ^ 1, k0 + 64);
    bf16x8 af[2][2], bf[4][2];
#pragma unroll
    for (int s = 0; s < 2; ++s)
#pragma unroll
      for (int kk = 0; kk < 2; ++kk)
        af[s][kk] = *(const bf16x8*)&As[cur][(wm * 32 + s * 16 + l16) * 64 +
                     ((kk * 32 + quad * 8) ^ ((l16 & 7) << 3))];
#pragma unroll
    for (int n = 0; n < 4; ++n)
#pragma unroll
      for (int kk = 0; kk < 2; ++kk)
        bf[n][kk] = *(const bf16x8*)&Bs[cur][(wn * 64 + n * 16 + l16) * 64 +
                     ((kk * 32 + quad * 8) ^ ((l16 & 7) << 3))];
#pragma unroll
    for (int kk = 0; kk < 2; ++kk)
#pragma unroll
      for (int s = 0; s < 2; ++s)
#pragma unroll
        for (int n = 0; n < 4; ++n)
          acc[s][n] = MFMA16(af[s][kk], bf[n][kk], acc[s][n]);
    cur ^= 1;
  }
#undef STAGE_OUT

#pragma unroll
  for (int n = 0; n < 4; ++n) {
    const int gn = colTile + wn * 64 + n * 16 + l16;
    const float bn = bias[gn];
#pragma unroll
    for (int s = 0; s < 2; ++s)
#pragma unroll
      for (int r = 0; r < 4; ++r) {
        const int gm = rowTile + wm * 32 + s * 16 + quad * 4 + r;
        out[(size_t)gm * 1024 + gn] = acc[s][n][r] + bn;
      }
  }
}

// =====================================================================
extern "C" void kernel_launch(void* const* d_in, const int* in_sizes, int n_in,
                              void* d_out, int out_size, void* d_ws, size_t ws_size,
                              hipStream_t stream) {
  (void)in_sizes; (void)n_in; (void)out_size; (void)ws_size;
  const float* x     = (const float*)d_in[0];
  const float* w_qkv = (const float*)d_in[1];
  const float* b_qkv = (const float*)d_in[2];
  const float* w_out = (const float*)d_in[3];
  const float* b_out = (const float*)d_in[4];
  float* out = (float*)d_out;

  u16* xb  = (u16*)d_ws;
  u16* wqb = xb + XN;
  u16* wob = wqb + WQN;
  u16* Qw  = wob + WON;
  u16* Vw  = Qw + (size_t)2 * Hc * Lc * Dc;
  u16* Vtw = Vw + (size_t)2 * Hc * Lc * Dc;
  u16* Aw  = Vtw + (size_t)2 * Hc * Lc * Dc;

  convert_all<<<7168, 256, 0, stream>>>(x, w_qkv, w_out, xb, wqb, wob);
  gemm_qv<<<512, 256, 0, stream>>>(xb, wqb, b_qkv, Qw, Vw, Vtw);
  attn_mfma<<<512, 256, 0, stream>>>(Qw, Vw, Vtw, Aw);
  gemm_out<<<512, 256, 0, stream>>>(Aw, wob, b_out, out);
}